// Round 1
// baseline (1882.992 us; speedup 1.0000x reference)
//
#include <hip/hip_runtime.h>
#include <math.h>

// Problem constants (match reference)
constexpr int Bb = 64;
constexpr int T  = 1024;
constexpr int DK = 64;
constexpr int QT = 8;     // q rows per block
constexpr int KT = 128;   // k rows per score tile
constexpr int KP4 = 17;   // padded K-tile row pitch in float4 (68 floats) -> breaks bank aliasing
constexpr float MASK_FILL_F = -4294967295.0f;  // float(-2^32+1)

__device__ __forceinline__ float4 shfl_xor_f4(float4 v, int m) {
    v.x = __shfl_xor(v.x, m, 64);
    v.y = __shfl_xor(v.y, m, 64);
    v.z = __shfl_xor(v.z, m, 64);
    v.w = __shfl_xor(v.w, m, 64);
    return v;
}

__global__ __launch_bounds__(256, 2)
void mha_fused_kernel(const float* __restrict__ Kp,   // key   [B,T,DK]
                      const float* __restrict__ Vp,   // value [B,T,DK]
                      const float* __restrict__ Qp,   // query [B,T,DK]
                      const int*   __restrict__ maskp,// mask  [B,T,T] (bool as i32)
                      const float* __restrict__ qmp,  // query_mask [B,T,T]
                      const float* __restrict__ gfp,  // gaussian_factor [B,T,T]
                      float* __restrict__ out_res,    // [B,T,DK]
                      float* __restrict__ out_attn)   // [B,T,T]
{
    __shared__ float4 sK4[KT * KP4];     // 34.8 KB K tile (reused as reduction buf in epilogue)
    __shared__ float  sS[QT][T];         // 32 KB score/prob rows
    __shared__ float4 sQ4[QT * 16];      // 2 KB Q tile

    const int b   = blockIdx.y;
    const int q0  = blockIdx.x * QT;
    const int tid = threadIdx.x;

    // ---- Load Q tile (contiguous 512 floats = 128 float4) ----
    const float4* Qg4 = reinterpret_cast<const float4*>(Qp + (b * T + q0) * DK);
    if (tid < QT * 16) sQ4[tid] = Qg4[tid];
    __syncthreads();

    // ---- Phase 1: scores  s = (Q.K^T)/8 - gf, masked ----
    // thread -> (kl = tid&127 within tile, qh = tid>>7 selects q group of 4)
    const int kl = tid & 127;
    const int qh = tid >> 7;

    for (int kt = 0; kt < T / KT; ++kt) {
        // stage K tile: KT*DK floats = 2048 float4, 8 per thread, coalesced
        const float4* Kg4 = reinterpret_cast<const float4*>(Kp + (b * T + kt * KT) * DK);
        #pragma unroll
        for (int i = 0; i < (KT * 16) / 256; ++i) {
            int fi = tid + i * 256;
            int r  = fi >> 4, dd = fi & 15;
            sK4[r * KP4 + dd] = Kg4[fi];
        }
        __syncthreads();

        float4 acc[4];
        #pragma unroll
        for (int j = 0; j < 4; ++j) acc[j] = make_float4(0.f, 0.f, 0.f, 0.f);

        #pragma unroll
        for (int dd = 0; dd < 16; ++dd) {
            float4 kv = sK4[kl * KP4 + dd];
            #pragma unroll
            for (int j = 0; j < 4; ++j) {
                float4 qv = sQ4[(qh * 4 + j) * 16 + dd];  // wave-uniform -> LDS broadcast
                acc[j].x += kv.x * qv.x;
                acc[j].y += kv.y * qv.y;
                acc[j].z += kv.z * qv.z;
                acc[j].w += kv.w * qv.w;
            }
        }

        const int kg = kt * KT + kl;
        #pragma unroll
        for (int j = 0; j < 4; ++j) {
            const int q = qh * 4 + j;
            float s = (acc[j].x + acc[j].y + acc[j].z + acc[j].w) * 0.125f;
            const int idx = (b * T + q0 + q) * T + kg;   // < 2^26, fits int
            s -= gfp[idx];
            if (maskp[idx] != 0) s = MASK_FILL_F;
            sS[q][kg] = s;
        }
        __syncthreads();
    }

    // ---- Phase 2: softmax per row (wave-owned: wave w handles rows 2w, 2w+1) ----
    const int lane = tid & 63;
    const int wv   = tid >> 6;

    #pragma unroll
    for (int r = 0; r < 2; ++r) {
        const int q = wv * 2 + r;
        float ev[16];
        float m = -INFINITY;
        #pragma unroll
        for (int i = 0; i < 16; ++i) {
            ev[i] = sS[q][lane + i * 64];
            m = fmaxf(m, ev[i]);
        }
        #pragma unroll
        for (int off = 32; off; off >>= 1) m = fmaxf(m, __shfl_xor(m, off, 64));

        float l = 0.f;
        #pragma unroll
        for (int i = 0; i < 16; ++i) {
            ev[i] = __expf(ev[i] - m);   // masked: exp(-4.3e9) -> 0
            l += ev[i];
        }
        #pragma unroll
        for (int off = 32; off; off >>= 1) l += __shfl_xor(l, off, 64);
        const float inv = 1.0f / l;

        const int rowbase = (b * T + q0 + q) * T;
        #pragma unroll
        for (int i = 0; i < 16; ++i) {
            const int k = lane + i * 64;
            const float p = ev[i] * inv * qmp[rowbase + k];
            sS[q][k] = p;
            out_attn[rowbase + k] = p;   // coalesced 256B/wave
        }
    }
    __syncthreads();

    // ---- Phase 3: result = P . V  (V read direct from global, each element once) ----
    const int d4 = tid & 15;     // float4 column of V row
    const int kg2 = tid >> 4;    // 0..15, k residue class
    float4 acc[QT];
    #pragma unroll
    for (int q = 0; q < QT; ++q) acc[q] = make_float4(0.f, 0.f, 0.f, 0.f);

    const float4* Vg4 = reinterpret_cast<const float4*>(Vp + b * T * DK);
    #pragma unroll 4
    for (int i = 0; i < 64; ++i) {
        const int k = i * 16 + kg2;
        const float4 vv = Vg4[k * 16 + d4];  // wave reads 1KB contiguous -> fully coalesced
        #pragma unroll
        for (int q = 0; q < QT; ++q) {
            const float p = sS[q][k];        // 4 distinct addrs/wave, broadcast, conflict-free
            acc[q].x += p * vv.x;
            acc[q].y += p * vv.y;
            acc[q].z += p * vv.z;
            acc[q].w += p * vv.w;
        }
    }

    // intra-wave reduce over the 4 k-residues within this wave (kg2 bits live in lane bits 4..5)
    #pragma unroll
    for (int q = 0; q < QT; ++q) {
        float4 t = shfl_xor_f4(acc[q], 16);
        acc[q].x += t.x; acc[q].y += t.y; acc[q].z += t.z; acc[q].w += t.w;
        t = shfl_xor_f4(acc[q], 32);
        acc[q].x += t.x; acc[q].y += t.y; acc[q].z += t.z; acc[q].w += t.w;
    }

    // cross-wave reduce via LDS (alias sK4 region: 4 waves * 8 q * 16 d4 float4 = 8KB)
    float4* red = sK4;
    if (lane < 16) {
        #pragma unroll
        for (int q = 0; q < QT; ++q)
            red[(wv * QT + q) * 16 + lane] = acc[q];
    }
    __syncthreads();

    if (tid < 128) {
        const int q  = tid >> 4;
        const int dd = tid & 15;
        float4 s0 = red[(0 * QT + q) * 16 + dd];
        float4 s1 = red[(1 * QT + q) * 16 + dd];
        float4 s2 = red[(2 * QT + q) * 16 + dd];
        float4 s3 = red[(3 * QT + q) * 16 + dd];
        float4 o;
        o.x = s0.x + s1.x + s2.x + s3.x;
        o.y = s0.y + s1.y + s2.y + s3.y;
        o.z = s0.z + s1.z + s2.z + s3.z;
        o.w = s0.w + s1.w + s2.w + s3.w;
        float4* Og4 = reinterpret_cast<float4*>(out_res + (b * T + q0) * DK);
        Og4[q * 16 + dd] = o;
    }
}

extern "C" void kernel_launch(void* const* d_in, const int* in_sizes, int n_in,
                              void* d_out, int out_size, void* d_ws, size_t ws_size,
                              hipStream_t stream) {
    const float* key   = (const float*)d_in[0];
    const float* value = (const float*)d_in[1];
    const float* query = (const float*)d_in[2];
    const int*   mask  = (const int*)d_in[3];
    const float* qmask = (const float*)d_in[4];
    const float* gauss = (const float*)d_in[5];

    float* out      = (float*)d_out;
    float* out_res  = out;                       // [B,T,DK]
    float* out_attn = out + Bb * T * DK;         // [B,T,T]

    dim3 grid(T / QT, Bb);
    dim3 block(256);
    mha_fused_kernel<<<grid, block, 0, stream>>>(key, value, query, mask, qmask, gauss,
                                                 out_res, out_attn);
}